// Round 1
// baseline (345.840 us; speedup 1.0000x reference)
//
#include <hip/hip_runtime.h>
#include <hip/hip_bf16.h>

#define NN 100000   // nodes
#define NE 1000000  // edges
#define EF 64       // edge features
#define IC 128      // in channels
#define OC 256      // out channels
// K = IC + EF = 192

typedef __attribute__((ext_vector_type(8))) short bf16x8;
typedef __attribute__((ext_vector_type(4))) float f32x4;

static __device__ __forceinline__ ushort f2bf(float f) {
  unsigned u = __float_as_uint(f);
  u += 0x7fffu + ((u >> 16) & 1u);   // RNE (inputs have no NaN)
  return (ushort)(u >> 16);
}

// ---- scatter: sums[t][f] += edge_attr[e][f] * edge_weight[e]; cnt[t] += 1 ----
__global__ __launch_bounds__(256) void scatter_kernel(
    const int* __restrict__ tgt, const float* __restrict__ ea,
    const float* __restrict__ ew, float* __restrict__ sums,
    float* __restrict__ cnt) {
  int lane = threadIdx.x & 63;
  int wave = (int)((blockIdx.x * blockDim.x + threadIdx.x) >> 6);
  int nwv = (int)((gridDim.x * blockDim.x) >> 6);
  for (int e = wave; e < NE; e += nwv) {
    int t = tgt[e];
    float w = ew[e];
    float v = ea[(size_t)e * EF + lane] * w;
    unsafeAtomicAdd(sums + (size_t)t * EF + lane, v);
    if (lane == 0) unsafeAtomicAdd(cnt + t, 1.0f);
  }
}

// ---- W prep: f32 [192][256] -> bf16 fragment-major buffer ----
// wfrag[((s*16+ct)*64+lane)*8+i] = bf16(W[s*32+(lane>>4)*8+i][ct*16+(lane&15)])
__global__ __launch_bounds__(256) void wprep_kernel(
    const float* __restrict__ W, ushort* __restrict__ wfrag) {
  int t = blockIdx.x * 256 + threadIdx.x;  // 0..49151
  int i = t & 7;
  int lane = (t >> 3) & 63;
  int ct = (t >> 9) & 15;
  int s = t >> 13;  // 0..5
  int k = s * 32 + (lane >> 4) * 8 + i;
  int col = ct * 16 + (lane & 15);
  wfrag[t] = f2bf(W[(size_t)k * OC + col]);
}

// ---- fused mean + concat + GEMM + bias + relu ----
// block = 256 thr = 4 waves; wave w handles rows blockIdx*64 + w*16 .. +15,
// all 256 output cols via 16 accumulators (16x16 tiles), K=192 in 6 mfma steps.
__global__ __launch_bounds__(256) void gemm_kernel(
    const float* __restrict__ na, const float* __restrict__ sums,
    const float* __restrict__ cnt, const float* __restrict__ nwt,
    const ushort* __restrict__ wfrag, const float* __restrict__ bias,
    float* __restrict__ out) {
  int tid = threadIdx.x;
  int lane = tid & 63;
  int wv = tid >> 6;
  int row_base = blockIdx.x * 64 + wv * 16;
  int r = row_base + (lane & 15);
  int rc = min(r, NN - 1);          // clamp tail; stores are guarded
  int kofs = (lane >> 4) * 8;       // element offset within a K=32 step
  int colb = lane & 15;

  const float* narow = na + (size_t)rc * IC;
  const float* srow = sums + (size_t)rc * EF;
  float scale = nwt[rc] / fmaxf(cnt[rc], 1.0f);

  // A fragments: steps 0..3 from node_attr, 4..5 from mean = sums*scale
  bf16x8 afrag[6];
#pragma unroll
  for (int s = 0; s < 4; ++s) {
    f32x4 lo = *(const f32x4*)(narow + s * 32 + kofs);
    f32x4 hi = *(const f32x4*)(narow + s * 32 + kofs + 4);
#pragma unroll
    for (int i = 0; i < 4; ++i) {
      afrag[s][i] = (short)f2bf(lo[i]);
      afrag[s][4 + i] = (short)f2bf(hi[i]);
    }
  }
#pragma unroll
  for (int s = 0; s < 2; ++s) {
    f32x4 lo = *(const f32x4*)(srow + s * 32 + kofs);
    f32x4 hi = *(const f32x4*)(srow + s * 32 + kofs + 4);
#pragma unroll
    for (int i = 0; i < 4; ++i) {
      afrag[4 + s][i] = (short)f2bf(lo[i] * scale);
      afrag[4 + s][4 + i] = (short)f2bf(hi[i] * scale);
    }
  }

  f32x4 acc[16];
#pragma unroll
  for (int ct = 0; ct < 16; ++ct) acc[ct] = (f32x4)(0.0f);

#pragma unroll
  for (int s = 0; s < 6; ++s) {
#pragma unroll
    for (int ct = 0; ct < 16; ++ct) {
      bf16x8 bfrag =
          *(const bf16x8*)(wfrag + ((size_t)((s * 16 + ct) * 64 + lane) * 8));
      acc[ct] =
          __builtin_amdgcn_mfma_f32_16x16x32_bf16(afrag[s], bfrag, acc[ct], 0, 0, 0);
    }
  }

  // C/D layout (m89-verified): col = lane&15, row = (lane>>4)*4 + reg
#pragma unroll
  for (int ct = 0; ct < 16; ++ct) {
    int col = ct * 16 + colb;
    float bv = bias[col];
#pragma unroll
    for (int i = 0; i < 4; ++i) {
      int rr = row_base + (lane >> 4) * 4 + i;
      if (rr < NN) out[(size_t)rr * OC + col] = fmaxf(acc[ct][i] + bv, 0.0f);
    }
  }
}

extern "C" void kernel_launch(void* const* d_in, const int* in_sizes, int n_in,
                              void* d_out, int out_size, void* d_ws, size_t ws_size,
                              hipStream_t stream) {
  const int* edge_index = (const int*)d_in[0];    // [2][NE], row 0 = targets
  const float* edge_attr = (const float*)d_in[1]; // [NE][EF]
  const float* node_attr = (const float*)d_in[2]; // [NN][IC]
  const float* edge_weight = (const float*)d_in[3];
  const float* node_weight = (const float*)d_in[4];
  const float* W = (const float*)d_in[5];         // [192][256]
  const float* bias = (const float*)d_in[6];
  float* out = (float*)d_out;

  float* sums = (float*)d_ws;                      // NN*EF f32 = 25.6 MB
  float* cnt = sums + (size_t)NN * EF;             // NN f32
  ushort* wfrag = (ushort*)((char*)d_ws + 26000000); // 98304 B, 16B-aligned

  hipMemsetAsync(d_ws, 0, ((size_t)NN * EF + NN) * sizeof(float), stream);
  wprep_kernel<<<192, 256, 0, stream>>>(W, wfrag);
  scatter_kernel<<<2048, 256, 0, stream>>>(edge_index, edge_attr, edge_weight,
                                           sums, cnt);
  gemm_kernel<<<(NN + 63) / 64, 256, 0, stream>>>(node_attr, sums, cnt,
                                                  node_weight, wfrag, bias, out);
}

// Round 2
// 322.856 us; speedup vs baseline: 1.0712x; 1.0712x over previous
//
#include <hip/hip_runtime.h>
#include <hip/hip_bf16.h>

#define NN 100000   // nodes
#define NE 1000000  // edges
#define EF 64       // edge features
#define IC 128      // in channels
#define OC 256      // out channels
#define NB1 391     // ceil(NN/256)

typedef __attribute__((ext_vector_type(8))) short bf16x8;
typedef __attribute__((ext_vector_type(4))) float f32x4;

static __device__ __forceinline__ ushort f2bf(float f) {
  unsigned u = __float_as_uint(f);
  u += 0x7fffu + ((u >> 16) & 1u);   // RNE (inputs have no NaN)
  return (ushort)(u >> 16);
}

// ---- 1. histogram of targets ----
__global__ __launch_bounds__(256) void hist_kernel(const int* __restrict__ tgt,
                                                   int* __restrict__ cnt) {
  int e = blockIdx.x * 256 + threadIdx.x;
  if (e < NE) atomicAdd(&cnt[tgt[e]], 1);
}

// ---- 2a. per-block (256-elem) sums of cnt ----
__global__ __launch_bounds__(256) void scan1_kernel(const int* __restrict__ cnt,
                                                    int* __restrict__ bsum) {
  __shared__ int s[256];
  int t = threadIdx.x;
  int i = blockIdx.x * 256 + t;
  s[t] = (i < NN) ? cnt[i] : 0;
  __syncthreads();
  for (int off = 128; off > 0; off >>= 1) {
    if (t < off) s[t] += s[t + off];
    __syncthreads();
  }
  if (t == 0) bsum[blockIdx.x] = s[0];
}

// ---- 2b. exclusive scan of NB1 block sums (single block) ----
__global__ __launch_bounds__(512) void scan2_kernel(const int* __restrict__ bsum,
                                                    int* __restrict__ boff) {
  __shared__ int s[512];
  int t = threadIdx.x;
  int v = (t < NB1) ? bsum[t] : 0;
  s[t] = v;
  __syncthreads();
  for (int off = 1; off < 512; off <<= 1) {
    int x = (t >= off) ? s[t - off] : 0;
    __syncthreads();
    s[t] += x;
    __syncthreads();
  }
  if (t < NB1) boff[t] = s[t] - v;  // exclusive
}

// ---- 2c. per-block exclusive scan + block offset -> offs, cursor ----
__global__ __launch_bounds__(256) void scan3_kernel(const int* __restrict__ cnt,
                                                    const int* __restrict__ boff,
                                                    int* __restrict__ offs,
                                                    int* __restrict__ cursor) {
  __shared__ int s[256];
  int t = threadIdx.x;
  int i = blockIdx.x * 256 + t;
  int v = (i < NN) ? cnt[i] : 0;
  s[t] = v;
  __syncthreads();
  for (int off = 1; off < 256; off <<= 1) {
    int x = (t >= off) ? s[t - off] : 0;
    __syncthreads();
    s[t] += x;
    __syncthreads();
  }
  if (i < NN) {
    int excl = s[t] - v + boff[blockIdx.x];
    offs[i] = excl;
    cursor[i] = excl;
    if (i == NN - 1) offs[NN] = excl + v;
  }
}

// ---- 3. bin edge ids into CSR order ----
__global__ __launch_bounds__(256) void place_kernel(const int* __restrict__ tgt,
                                                    int* __restrict__ cursor,
                                                    int* __restrict__ eid) {
  int e = blockIdx.x * 256 + threadIdx.x;
  if (e < NE) {
    int pos = atomicAdd(&cursor[tgt[e]], 1);
    eid[pos] = e;
  }
}

// ---- 4. gather-aggregate: one wave per node, lane = feature ----
// mean_bf[n][f] = bf16( nwt[n]/max(cnt,1) * sum_e ea[e][f]*ew[e] )
__global__ __launch_bounds__(256) void agg_kernel(
    const int* __restrict__ offs, const int* __restrict__ eid,
    const float* __restrict__ ea, const float* __restrict__ ew,
    const float* __restrict__ nwt, ushort* __restrict__ mean_bf) {
  int lane = threadIdx.x & 63;
  int n = blockIdx.x * 4 + (threadIdx.x >> 6);
  if (n >= NN) return;
  int j = offs[n], jend = offs[n + 1];
  int deg = jend - j;
  float acc = 0.0f;
  for (; j + 1 < jend; j += 2) {
    int e0 = eid[j], e1 = eid[j + 1];
    float w0 = ew[e0], w1 = ew[e1];
    float a0 = ea[(size_t)e0 * EF + lane];
    float a1 = ea[(size_t)e1 * EF + lane];
    acc += a0 * w0;
    acc += a1 * w1;
  }
  if (j < jend) {
    int e0 = eid[j];
    acc += ea[(size_t)e0 * EF + lane] * ew[e0];
  }
  float scale = nwt[n] / (float)max(deg, 1);
  mean_bf[(size_t)n * EF + lane] = f2bf(acc * scale);
}

// ---- W prep: f32 [192][256] -> bf16 fragment-major buffer ----
__global__ __launch_bounds__(256) void wprep_kernel(
    const float* __restrict__ W, ushort* __restrict__ wfrag) {
  int t = blockIdx.x * 256 + threadIdx.x;  // 0..49151
  int i = t & 7;
  int lane = (t >> 3) & 63;
  int ct = (t >> 9) & 15;
  int s = t >> 13;  // 0..5
  int k = s * 32 + (lane >> 4) * 8 + i;
  int col = ct * 16 + (lane & 15);
  wfrag[t] = f2bf(W[(size_t)k * OC + col]);
}

// ---- fused concat + GEMM + bias + relu ----
__global__ __launch_bounds__(256) void gemm_kernel(
    const float* __restrict__ na, const ushort* __restrict__ mean_bf,
    const ushort* __restrict__ wfrag, const float* __restrict__ bias,
    float* __restrict__ out) {
  int tid = threadIdx.x;
  int lane = tid & 63;
  int wv = tid >> 6;
  int row_base = blockIdx.x * 64 + wv * 16;
  int r = row_base + (lane & 15);
  int rc = min(r, NN - 1);          // clamp tail; stores are guarded
  int kofs = (lane >> 4) * 8;       // element offset within a K=32 step
  int colb = lane & 15;

  const float* narow = na + (size_t)rc * IC;
  const ushort* mrow = mean_bf + (size_t)rc * EF;

  bf16x8 afrag[6];
#pragma unroll
  for (int s = 0; s < 4; ++s) {
    f32x4 lo = *(const f32x4*)(narow + s * 32 + kofs);
    f32x4 hi = *(const f32x4*)(narow + s * 32 + kofs + 4);
#pragma unroll
    for (int i = 0; i < 4; ++i) {
      afrag[s][i] = (short)f2bf(lo[i]);
      afrag[s][4 + i] = (short)f2bf(hi[i]);
    }
  }
#pragma unroll
  for (int s = 0; s < 2; ++s)
    afrag[4 + s] = *(const bf16x8*)(mrow + s * 32 + kofs);

  f32x4 acc[16];
#pragma unroll
  for (int ct = 0; ct < 16; ++ct) acc[ct] = (f32x4)(0.0f);

#pragma unroll
  for (int s = 0; s < 6; ++s) {
#pragma unroll
    for (int ct = 0; ct < 16; ++ct) {
      bf16x8 bfrag =
          *(const bf16x8*)(wfrag + ((size_t)((s * 16 + ct) * 64 + lane) * 8));
      acc[ct] =
          __builtin_amdgcn_mfma_f32_16x16x32_bf16(afrag[s], bfrag, acc[ct], 0, 0, 0);
    }
  }

  // C/D layout (m89-verified): col = lane&15, row = (lane>>4)*4 + reg
#pragma unroll
  for (int ct = 0; ct < 16; ++ct) {
    int col = ct * 16 + colb;
    float bv = bias[col];
#pragma unroll
    for (int i = 0; i < 4; ++i) {
      int rr = row_base + (lane >> 4) * 4 + i;
      if (rr < NN) out[(size_t)rr * OC + col] = fmaxf(acc[ct][i] + bv, 0.0f);
    }
  }
}

extern "C" void kernel_launch(void* const* d_in, const int* in_sizes, int n_in,
                              void* d_out, int out_size, void* d_ws, size_t ws_size,
                              hipStream_t stream) {
  const int* edge_index = (const int*)d_in[0];    // [2][NE], row 0 = targets
  const float* edge_attr = (const float*)d_in[1]; // [NE][EF]
  const float* node_attr = (const float*)d_in[2]; // [NN][IC]
  const float* edge_weight = (const float*)d_in[3];
  const float* node_weight = (const float*)d_in[4];
  const float* W = (const float*)d_in[5];         // [192][256]
  const float* bias = (const float*)d_in[6];
  float* out = (float*)d_out;

  char* p = (char*)d_ws;
  ushort* mean_bf = (ushort*)p;                    // 12,800,000 B
  int* eid       = (int*)(p + 12800000);           // 4,000,000 B
  int* cnt       = (int*)(p + 16800000);           // 400,000 B
  int* offs      = (int*)(p + 17200000);           // 400,004 -> pad 400,016
  int* cursor    = (int*)(p + 17600016);           // 400,000 B
  int* bsum      = (int*)(p + 18000016);           // 1,568 B
  int* boff      = (int*)(p + 18001584);           // 1,568 B
  ushort* wfrag  = (ushort*)(p + 18003152);        // 98,304 B (16B-aligned)

  hipMemsetAsync(cnt, 0, NN * sizeof(int), stream);
  wprep_kernel<<<192, 256, 0, stream>>>(W, wfrag);
  hist_kernel<<<(NE + 255) / 256, 256, 0, stream>>>(edge_index, cnt);
  scan1_kernel<<<NB1, 256, 0, stream>>>(cnt, bsum);
  scan2_kernel<<<1, 512, 0, stream>>>(bsum, boff);
  scan3_kernel<<<NB1, 256, 0, stream>>>(cnt, boff, offs, cursor);
  place_kernel<<<(NE + 255) / 256, 256, 0, stream>>>(edge_index, cursor, eid);
  agg_kernel<<<(NN + 3) / 4, 256, 0, stream>>>(offs, eid, edge_attr,
                                               edge_weight, node_weight, mean_bf);
  gemm_kernel<<<(NN + 63) / 64, 256, 0, stream>>>(node_attr, mean_bf, wfrag,
                                                  bias, out);
}

// Round 3
// 270.249 us; speedup vs baseline: 1.2797x; 1.1947x over previous
//
#include <hip/hip_runtime.h>
#include <hip/hip_bf16.h>

#define NN 100000   // nodes
#define NE 1000000  // edges
#define EF 64       // edge features
#define IC 128      // in channels
#define OC 256      // out channels
#define NB1 391     // ceil(NN/256)

typedef __attribute__((ext_vector_type(8))) short bf16x8;
typedef __attribute__((ext_vector_type(4))) float f32x4;

static __device__ __forceinline__ ushort f2bf(float f) {
  unsigned u = __float_as_uint(f);
  u += 0x7fffu + ((u >> 16) & 1u);   // RNE (inputs have no NaN)
  return (ushort)(u >> 16);
}

// ---- 1. histogram of targets ----
__global__ __launch_bounds__(256) void hist_kernel(const int* __restrict__ tgt,
                                                   int* __restrict__ cnt) {
  int e = blockIdx.x * 256 + threadIdx.x;
  if (e < NE) atomicAdd(&cnt[tgt[e]], 1);
}

// ---- 2a. per-block (256-elem) sums of cnt ----
__global__ __launch_bounds__(256) void scan1_kernel(const int* __restrict__ cnt,
                                                    int* __restrict__ bsum) {
  __shared__ int s[256];
  int t = threadIdx.x;
  int i = blockIdx.x * 256 + t;
  s[t] = (i < NN) ? cnt[i] : 0;
  __syncthreads();
  for (int off = 128; off > 0; off >>= 1) {
    if (t < off) s[t] += s[t + off];
    __syncthreads();
  }
  if (t == 0) bsum[blockIdx.x] = s[0];
}

// ---- 2b. exclusive scan of NB1 block sums (single block) ----
__global__ __launch_bounds__(512) void scan2_kernel(const int* __restrict__ bsum,
                                                    int* __restrict__ boff) {
  __shared__ int s[512];
  int t = threadIdx.x;
  int v = (t < NB1) ? bsum[t] : 0;
  s[t] = v;
  __syncthreads();
  for (int off = 1; off < 512; off <<= 1) {
    int x = (t >= off) ? s[t - off] : 0;
    __syncthreads();
    s[t] += x;
    __syncthreads();
  }
  if (t < NB1) boff[t] = s[t] - v;  // exclusive
}

// ---- 2c. per-block exclusive scan + block offset -> offs, cursor ----
__global__ __launch_bounds__(256) void scan3_kernel(const int* __restrict__ cnt,
                                                    const int* __restrict__ boff,
                                                    int* __restrict__ offs,
                                                    int* __restrict__ cursor) {
  __shared__ int s[256];
  int t = threadIdx.x;
  int i = blockIdx.x * 256 + t;
  int v = (i < NN) ? cnt[i] : 0;
  s[t] = v;
  __syncthreads();
  for (int off = 1; off < 256; off <<= 1) {
    int x = (t >= off) ? s[t - off] : 0;
    __syncthreads();
    s[t] += x;
    __syncthreads();
  }
  if (i < NN) {
    int excl = s[t] - v + boff[blockIdx.x];
    offs[i] = excl;
    cursor[i] = excl;
    if (i == NN - 1) offs[NN] = excl + v;
  }
}

// ---- 3. bin edge ids + weights into CSR order ----
__global__ __launch_bounds__(256) void place_kernel(const int* __restrict__ tgt,
                                                    const float* __restrict__ ew,
                                                    int* __restrict__ cursor,
                                                    int* __restrict__ eid,
                                                    float* __restrict__ ews) {
  int e = blockIdx.x * 256 + threadIdx.x;
  if (e < NE) {
    int pos = atomicAdd(&cursor[tgt[e]], 1);
    eid[pos] = e;
    ews[pos] = ew[e];
  }
}

// ---- 4. gather-aggregate: one wave per node; lane = (edge-slot, feat-quad) ----
// 8 edges in flight per iteration; float4 per lane; shfl_xor cross-slot reduce.
__global__ __launch_bounds__(256) void agg_kernel(
    const int* __restrict__ offs, const int* __restrict__ eid,
    const float* __restrict__ ews, const float* __restrict__ ea,
    const float* __restrict__ nwt, ushort* __restrict__ mean_bf) {
  int lane = threadIdx.x & 63;
  int n = blockIdx.x * 4 + (threadIdx.x >> 6);
  if (n >= NN) return;
  int jbeg = offs[n], jend = offs[n + 1];
  int deg = jend - jbeg;
  int eg = lane >> 4;   // edge slot 0..3
  int fq = lane & 15;   // feature quad -> floats 4*fq..4*fq+3

  f32x4 acc = (f32x4)(0.0f);
  for (int j = jbeg; j < jend; j += 8) {
    int i0 = j + eg, i1 = j + 4 + eg;
    int c0 = min(i0, jend - 1), c1 = min(i1, jend - 1);
    float w0 = (i0 < jend) ? ews[c0] : 0.0f;
    float w1 = (i1 < jend) ? ews[c1] : 0.0f;
    int e0 = eid[c0], e1 = eid[c1];
    f32x4 v0 = *(const f32x4*)(ea + (size_t)e0 * EF + fq * 4);
    f32x4 v1 = *(const f32x4*)(ea + (size_t)e1 * EF + fq * 4);
    acc += v0 * w0;
    acc += v1 * w1;
  }

  // reduce across the 4 edge slots (lane bits 4,5)
#pragma unroll
  for (int m = 16; m <= 32; m <<= 1) {
    f32x4 o;
#pragma unroll
    for (int i = 0; i < 4; ++i) o[i] = __shfl_xor(acc[i], m, 64);
    acc += o;
  }

  if (lane < 16) {
    float scale = nwt[n] / (float)max(deg, 1);
    ushort4 o;
    o.x = f2bf(acc[0] * scale);
    o.y = f2bf(acc[1] * scale);
    o.z = f2bf(acc[2] * scale);
    o.w = f2bf(acc[3] * scale);
    *(ushort4*)(mean_bf + (size_t)n * EF + fq * 4) = o;
  }
}

// ---- W prep: f32 [192][256] -> bf16 fragment-major buffer ----
__global__ __launch_bounds__(256) void wprep_kernel(
    const float* __restrict__ W, ushort* __restrict__ wfrag) {
  int t = blockIdx.x * 256 + threadIdx.x;  // 0..49151
  int i = t & 7;
  int lane = (t >> 3) & 63;
  int ct = (t >> 9) & 15;
  int s = t >> 13;  // 0..5
  int k = s * 32 + (lane >> 4) * 8 + i;
  int col = ct * 16 + (lane & 15);
  wfrag[t] = f2bf(W[(size_t)k * OC + col]);
}

// ---- fused concat + GEMM + bias + relu ----
__global__ __launch_bounds__(256) void gemm_kernel(
    const float* __restrict__ na, const ushort* __restrict__ mean_bf,
    const ushort* __restrict__ wfrag, const float* __restrict__ bias,
    float* __restrict__ out) {
  int tid = threadIdx.x;
  int lane = tid & 63;
  int wv = tid >> 6;
  int row_base = blockIdx.x * 64 + wv * 16;
  int r = row_base + (lane & 15);
  int rc = min(r, NN - 1);          // clamp tail; stores are guarded
  int kofs = (lane >> 4) * 8;       // element offset within a K=32 step
  int colb = lane & 15;

  const float* narow = na + (size_t)rc * IC;
  const ushort* mrow = mean_bf + (size_t)rc * EF;

  bf16x8 afrag[6];
#pragma unroll
  for (int s = 0; s < 4; ++s) {
    f32x4 lo = *(const f32x4*)(narow + s * 32 + kofs);
    f32x4 hi = *(const f32x4*)(narow + s * 32 + kofs + 4);
#pragma unroll
    for (int i = 0; i < 4; ++i) {
      afrag[s][i] = (short)f2bf(lo[i]);
      afrag[s][4 + i] = (short)f2bf(hi[i]);
    }
  }
#pragma unroll
  for (int s = 0; s < 2; ++s)
    afrag[4 + s] = *(const bf16x8*)(mrow + s * 32 + kofs);

  f32x4 acc[16];
#pragma unroll
  for (int ct = 0; ct < 16; ++ct) acc[ct] = (f32x4)(0.0f);

#pragma unroll
  for (int s = 0; s < 6; ++s) {
#pragma unroll
    for (int ct = 0; ct < 16; ++ct) {
      bf16x8 bfrag =
          *(const bf16x8*)(wfrag + ((size_t)((s * 16 + ct) * 64 + lane) * 8));
      acc[ct] =
          __builtin_amdgcn_mfma_f32_16x16x32_bf16(afrag[s], bfrag, acc[ct], 0, 0, 0);
    }
  }

  // C/D layout (m89-verified): col = lane&15, row = (lane>>4)*4 + reg
#pragma unroll
  for (int ct = 0; ct < 16; ++ct) {
    int col = ct * 16 + colb;
    float bv = bias[col];
#pragma unroll
    for (int i = 0; i < 4; ++i) {
      int rr = row_base + (lane >> 4) * 4 + i;
      if (rr < NN) out[(size_t)rr * OC + col] = fmaxf(acc[ct][i] + bv, 0.0f);
    }
  }
}

extern "C" void kernel_launch(void* const* d_in, const int* in_sizes, int n_in,
                              void* d_out, int out_size, void* d_ws, size_t ws_size,
                              hipStream_t stream) {
  const int* edge_index = (const int*)d_in[0];    // [2][NE], row 0 = targets
  const float* edge_attr = (const float*)d_in[1]; // [NE][EF]
  const float* node_attr = (const float*)d_in[2]; // [NN][IC]
  const float* edge_weight = (const float*)d_in[3];
  const float* node_weight = (const float*)d_in[4];
  const float* W = (const float*)d_in[5];         // [192][256]
  const float* bias = (const float*)d_in[6];
  float* out = (float*)d_out;

  char* p = (char*)d_ws;
  ushort* mean_bf = (ushort*)p;                    // 12,800,000 B
  int* eid       = (int*)(p + 12800000);           // 4,000,000 B
  float* ews     = (float*)(p + 16800000);         // 4,000,000 B
  int* cnt       = (int*)(p + 20800000);           // 400,000 B
  int* offs      = (int*)(p + 21200000);           // 400,016 B
  int* cursor    = (int*)(p + 21600016);           // 400,000 B
  int* bsum      = (int*)(p + 22000016);           // 1,568 B
  int* boff      = (int*)(p + 22001584);           // 1,568 B
  ushort* wfrag  = (ushort*)(p + 22003152);        // 98,304 B (16B-aligned)

  hipMemsetAsync(cnt, 0, NN * sizeof(int), stream);
  wprep_kernel<<<192, 256, 0, stream>>>(W, wfrag);
  hist_kernel<<<(NE + 255) / 256, 256, 0, stream>>>(edge_index, cnt);
  scan1_kernel<<<NB1, 256, 0, stream>>>(cnt, bsum);
  scan2_kernel<<<1, 512, 0, stream>>>(bsum, boff);
  scan3_kernel<<<NB1, 256, 0, stream>>>(cnt, boff, offs, cursor);
  place_kernel<<<(NE + 255) / 256, 256, 0, stream>>>(edge_index, edge_weight,
                                                     cursor, eid, ews);
  agg_kernel<<<(NN + 3) / 4, 256, 0, stream>>>(offs, eid, ews, edge_attr,
                                               node_weight, mean_bf);
  gemm_kernel<<<(NN + 63) / 64, 256, 0, stream>>>(node_attr, mean_bf, wfrag,
                                                  bias, out);
}

// Round 4
// 253.130 us; speedup vs baseline: 1.3663x; 1.0676x over previous
//
#include <hip/hip_runtime.h>
#include <hip/hip_bf16.h>

#define NN 100000   // nodes
#define NE 1000000  // edges
#define EF 64       // edge features
#define IC 128      // in channels
#define OC 256      // out channels
#define NB1 391     // ceil(NN/256)

typedef __attribute__((ext_vector_type(8))) short bf16x8;
typedef __attribute__((ext_vector_type(4))) float f32x4;

static __device__ __forceinline__ ushort f2bf(float f) {
  unsigned u = __float_as_uint(f);
  u += 0x7fffu + ((u >> 16) & 1u);   // RNE (inputs have no NaN)
  return (ushort)(u >> 16);
}

// ---- 1. histogram of targets (4 edges/thread) ----
__global__ __launch_bounds__(256) void hist_kernel(const int4* __restrict__ tgt4,
                                                   int* __restrict__ cnt) {
  int q = blockIdx.x * 256 + threadIdx.x;
  if (q < NE / 4) {
    int4 t = tgt4[q];
    atomicAdd(&cnt[t.x], 1);
    atomicAdd(&cnt[t.y], 1);
    atomicAdd(&cnt[t.z], 1);
    atomicAdd(&cnt[t.w], 1);
  }
}

// ---- 2a. per-block (256-elem) sums of cnt ----
__global__ __launch_bounds__(256) void scan1_kernel(const int* __restrict__ cnt,
                                                    int* __restrict__ bsum) {
  __shared__ int s[256];
  int t = threadIdx.x;
  int i = blockIdx.x * 256 + t;
  s[t] = (i < NN) ? cnt[i] : 0;
  __syncthreads();
  for (int off = 128; off > 0; off >>= 1) {
    if (t < off) s[t] += s[t + off];
    __syncthreads();
  }
  if (t == 0) bsum[blockIdx.x] = s[0];
}

// ---- 2b. block offset (re-sum of bsum[0..b-1]) + local scan -> offs, cursor ----
__global__ __launch_bounds__(256) void scan23_kernel(const int* __restrict__ cnt,
                                                     const int* __restrict__ bsum,
                                                     int* __restrict__ offs,
                                                     int* __restrict__ cursor) {
  __shared__ int s[256];
  __shared__ int base_s;
  int t = threadIdx.x;
  int b = blockIdx.x;
  int part = 0;
  for (int i = t; i < b; i += 256) part += bsum[i];
  s[t] = part;
  __syncthreads();
  for (int off = 128; off > 0; off >>= 1) {
    if (t < off) s[t] += s[t + off];
    __syncthreads();
  }
  if (t == 0) base_s = s[0];
  __syncthreads();
  int base = base_s;
  int i = b * 256 + t;
  int v = (i < NN) ? cnt[i] : 0;
  s[t] = v;
  __syncthreads();
  for (int off = 1; off < 256; off <<= 1) {
    int x = (t >= off) ? s[t - off] : 0;
    __syncthreads();
    s[t] += x;
    __syncthreads();
  }
  if (i < NN) {
    int excl = s[t] - v + base;
    offs[i] = excl;
    cursor[i] = excl;
    if (i == NN - 1) offs[NN] = excl + v;
  }
}

// ---- 3. bin edge ids + weights into CSR order (4 edges/thread) ----
__global__ __launch_bounds__(256) void place_kernel(const int4* __restrict__ tgt4,
                                                    const float4* __restrict__ ew4,
                                                    int* __restrict__ cursor,
                                                    int* __restrict__ eid,
                                                    float* __restrict__ ews) {
  int q = blockIdx.x * 256 + threadIdx.x;
  if (q < NE / 4) {
    int4 t = tgt4[q];
    float4 w = ew4[q];
    int e = q * 4;
    int p;
    p = atomicAdd(&cursor[t.x], 1); eid[p] = e;     ews[p] = w.x;
    p = atomicAdd(&cursor[t.y], 1); eid[p] = e + 1; ews[p] = w.y;
    p = atomicAdd(&cursor[t.z], 1); eid[p] = e + 2; ews[p] = w.z;
    p = atomicAdd(&cursor[t.w], 1); eid[p] = e + 3; ews[p] = w.w;
  }
}

// ---- 4. gather-aggregate: one wave per node; 16 edges in flight ----
__global__ __launch_bounds__(256) void agg_kernel(
    const int* __restrict__ offs, const int* __restrict__ eid,
    const float* __restrict__ ews, const float* __restrict__ ea,
    const float* __restrict__ nwt, ushort* __restrict__ mean_bf) {
  int lane = threadIdx.x & 63;
  int n = blockIdx.x * 4 + (threadIdx.x >> 6);
  if (n >= NN) return;
  int jbeg = offs[n], jend = offs[n + 1];
  int deg = jend - jbeg;
  int eg = lane >> 4;   // edge slot 0..3
  int fq = lane & 15;   // feature quad -> floats 4*fq..4*fq+3

  f32x4 acc = (f32x4)(0.0f);
  for (int j = jbeg; j < jend; j += 16) {
#pragma unroll
    for (int u = 0; u < 4; ++u) {
      int i = j + u * 4 + eg;
      int c = min(i, jend - 1);
      float w = (i < jend) ? ews[c] : 0.0f;
      int e = eid[c];
      f32x4 v = *(const f32x4*)(ea + (size_t)e * EF + fq * 4);
      acc += v * w;
    }
  }

  // reduce across the 4 edge slots (lane bits 4,5)
#pragma unroll
  for (int m = 16; m <= 32; m <<= 1) {
    f32x4 o;
#pragma unroll
    for (int i = 0; i < 4; ++i) o[i] = __shfl_xor(acc[i], m, 64);
    acc += o;
  }

  if (lane < 16) {
    float scale = nwt[n] / (float)max(deg, 1);
    ushort4 o;
    o.x = f2bf(acc[0] * scale);
    o.y = f2bf(acc[1] * scale);
    o.z = f2bf(acc[2] * scale);
    o.w = f2bf(acc[3] * scale);
    *(ushort4*)(mean_bf + (size_t)n * EF + fq * 4) = o;
  }
}

// ---- W prep: f32 [192][256] -> bf16 fragment-major buffer ----
__global__ __launch_bounds__(256) void wprep_kernel(
    const float* __restrict__ W, ushort* __restrict__ wfrag) {
  int t = blockIdx.x * 256 + threadIdx.x;  // 0..49151
  int i = t & 7;
  int lane = (t >> 3) & 63;
  int ct = (t >> 9) & 15;
  int s = t >> 13;  // 0..5
  int k = s * 32 + (lane >> 4) * 8 + i;
  int col = ct * 16 + (lane & 15);
  wfrag[t] = f2bf(W[(size_t)k * OC + col]);
}

// ---- fused concat + GEMM + bias + relu ----
__global__ __launch_bounds__(256) void gemm_kernel(
    const float* __restrict__ na, const ushort* __restrict__ mean_bf,
    const ushort* __restrict__ wfrag, const float* __restrict__ bias,
    float* __restrict__ out) {
  int tid = threadIdx.x;
  int lane = tid & 63;
  int wv = tid >> 6;
  int row_base = blockIdx.x * 64 + wv * 16;
  int r = row_base + (lane & 15);
  int rc = min(r, NN - 1);          // clamp tail; stores are guarded
  int kofs = (lane >> 4) * 8;       // element offset within a K=32 step
  int colb = lane & 15;

  const float* narow = na + (size_t)rc * IC;
  const ushort* mrow = mean_bf + (size_t)rc * EF;

  bf16x8 afrag[6];
#pragma unroll
  for (int s = 0; s < 4; ++s) {
    f32x4 lo = *(const f32x4*)(narow + s * 32 + kofs);
    f32x4 hi = *(const f32x4*)(narow + s * 32 + kofs + 4);
#pragma unroll
    for (int i = 0; i < 4; ++i) {
      afrag[s][i] = (short)f2bf(lo[i]);
      afrag[s][4 + i] = (short)f2bf(hi[i]);
    }
  }
#pragma unroll
  for (int s = 0; s < 2; ++s)
    afrag[4 + s] = *(const bf16x8*)(mrow + s * 32 + kofs);

  f32x4 acc[16];
#pragma unroll
  for (int ct = 0; ct < 16; ++ct) acc[ct] = (f32x4)(0.0f);

#pragma unroll
  for (int s = 0; s < 6; ++s) {
#pragma unroll
    for (int ct = 0; ct < 16; ++ct) {
      bf16x8 bfrag =
          *(const bf16x8*)(wfrag + ((size_t)((s * 16 + ct) * 64 + lane) * 8));
      acc[ct] =
          __builtin_amdgcn_mfma_f32_16x16x32_bf16(afrag[s], bfrag, acc[ct], 0, 0, 0);
    }
  }

  // C/D layout (m89-verified): col = lane&15, row = (lane>>4)*4 + reg
#pragma unroll
  for (int ct = 0; ct < 16; ++ct) {
    int col = ct * 16 + colb;
    float bv = bias[col];
#pragma unroll
    for (int i = 0; i < 4; ++i) {
      int rr = row_base + (lane >> 4) * 4 + i;
      if (rr < NN) {
        float v = fmaxf(acc[ct][i] + bv, 0.0f);
        __builtin_nontemporal_store(v, out + (size_t)rr * OC + col);
      }
    }
  }
}

extern "C" void kernel_launch(void* const* d_in, const int* in_sizes, int n_in,
                              void* d_out, int out_size, void* d_ws, size_t ws_size,
                              hipStream_t stream) {
  const int* edge_index = (const int*)d_in[0];    // [2][NE], row 0 = targets
  const float* edge_attr = (const float*)d_in[1]; // [NE][EF]
  const float* node_attr = (const float*)d_in[2]; // [NN][IC]
  const float* edge_weight = (const float*)d_in[3];
  const float* node_weight = (const float*)d_in[4];
  const float* W = (const float*)d_in[5];         // [192][256]
  const float* bias = (const float*)d_in[6];
  float* out = (float*)d_out;

  char* p = (char*)d_ws;
  ushort* mean_bf = (ushort*)p;                    // 12,800,000 B
  int* eid       = (int*)(p + 12800000);           // 4,000,000 B
  float* ews     = (float*)(p + 16800000);         // 4,000,000 B
  int* cnt       = (int*)(p + 20800000);           // 400,000 B
  int* offs      = (int*)(p + 21200000);           // 400,016 B
  int* cursor    = (int*)(p + 21600016);           // 400,000 B
  int* bsum      = (int*)(p + 22000016);           // 1,568 B
  ushort* wfrag  = (ushort*)(p + 22001600);        // 98,304 B (16B-aligned)

  hipMemsetAsync(cnt, 0, NN * sizeof(int), stream);
  wprep_kernel<<<192, 256, 0, stream>>>(W, wfrag);
  hist_kernel<<<(NE / 4 + 255) / 256, 256, 0, stream>>>((const int4*)edge_index,
                                                        cnt);
  scan1_kernel<<<NB1, 256, 0, stream>>>(cnt, bsum);
  scan23_kernel<<<NB1, 256, 0, stream>>>(cnt, bsum, offs, cursor);
  place_kernel<<<(NE / 4 + 255) / 256, 256, 0, stream>>>(
      (const int4*)edge_index, (const float4*)edge_weight, cursor, eid, ews);
  agg_kernel<<<(NN + 3) / 4, 256, 0, stream>>>(offs, eid, ews, edge_attr,
                                               node_weight, mean_bf);
  gemm_kernel<<<(NN + 63) / 64, 256, 0, stream>>>(node_attr, mean_bf, wfrag,
                                                  bias, out);
}

// Round 7
// 251.208 us; speedup vs baseline: 1.3767x; 1.0076x over previous
//
#include <hip/hip_runtime.h>
#include <hip/hip_bf16.h>

#define NN 100000   // nodes
#define NE 1000000  // edges
#define EF 64       // edge features
#define IC 128      // in channels
#define OC 256      // out channels
#define NB1 391     // ceil(NN/256)

typedef __attribute__((ext_vector_type(8))) short bf16x8;
typedef __attribute__((ext_vector_type(4))) float f32x4;

static __device__ __forceinline__ ushort f2bf(float f) {
  unsigned u = __float_as_uint(f);
  u += 0x7fffu + ((u >> 16) & 1u);   // RNE (inputs have no NaN)
  return (ushort)(u >> 16);
}

// ---- 0. W prep (f32 [192][256] -> bf16 fragment-major) + zero cnt ----
// Runs before hist_kernel on the same stream, so cnt is zeroed in time.
__global__ __launch_bounds__(256) void wprep_kernel(
    const float* __restrict__ W, ushort* __restrict__ wfrag,
    int* __restrict__ cnt) {
  int t = blockIdx.x * 256 + threadIdx.x;  // 0..49151
  int i = t & 7;
  int lane = (t >> 3) & 63;
  int ct = (t >> 9) & 15;
  int s = t >> 13;  // 0..5
  int k = s * 32 + (lane >> 4) * 8 + i;
  int col = ct * 16 + (lane & 15);
  wfrag[t] = f2bf(W[(size_t)k * OC + col]);
  for (int j = t; j < NN; j += 192 * 256) cnt[j] = 0;
}

// ---- 1. histogram of targets (4 edges/thread) ----
__global__ __launch_bounds__(256) void hist_kernel(const int4* __restrict__ tgt4,
                                                   int* __restrict__ cnt) {
  int q = blockIdx.x * 256 + threadIdx.x;
  if (q < NE / 4) {
    int4 t = tgt4[q];
    atomicAdd(&cnt[t.x], 1);
    atomicAdd(&cnt[t.y], 1);
    atomicAdd(&cnt[t.z], 1);
    atomicAdd(&cnt[t.w], 1);
  }
}

// ---- 2a. per-block (256-elem) sums of cnt ----
__global__ __launch_bounds__(256) void scan1_kernel(const int* __restrict__ cnt,
                                                    int* __restrict__ bsum) {
  __shared__ int s[256];
  int t = threadIdx.x;
  int i = blockIdx.x * 256 + t;
  s[t] = (i < NN) ? cnt[i] : 0;
  __syncthreads();
  for (int off = 128; off > 0; off >>= 1) {
    if (t < off) s[t] += s[t + off];
    __syncthreads();
  }
  if (t == 0) bsum[blockIdx.x] = s[0];
}

// ---- 2b. block offset (re-sum of bsum[0..b-1]) + local scan -> offs, cursor ----
__global__ __launch_bounds__(256) void scan23_kernel(const int* __restrict__ cnt,
                                                     const int* __restrict__ bsum,
                                                     int* __restrict__ offs,
                                                     int* __restrict__ cursor) {
  __shared__ int s[256];
  __shared__ int base_s;
  int t = threadIdx.x;
  int b = blockIdx.x;
  int part = 0;
  for (int i = t; i < b; i += 256) part += bsum[i];
  s[t] = part;
  __syncthreads();
  for (int off = 128; off > 0; off >>= 1) {
    if (t < off) s[t] += s[t + off];
    __syncthreads();
  }
  if (t == 0) base_s = s[0];
  __syncthreads();
  int base = base_s;
  int i = b * 256 + t;
  int v = (i < NN) ? cnt[i] : 0;
  s[t] = v;
  __syncthreads();
  for (int off = 1; off < 256; off <<= 1) {
    int x = (t >= off) ? s[t - off] : 0;
    __syncthreads();
    s[t] += x;
    __syncthreads();
  }
  if (i < NN) {
    int excl = s[t] - v + base;
    offs[i] = excl;
    cursor[i] = excl;
    if (i == NN - 1) offs[NN] = excl + v;
  }
}

// ---- 3. bin edge ids + weights into CSR order (4 edges/thread) ----
__global__ __launch_bounds__(256) void place_kernel(const int4* __restrict__ tgt4,
                                                    const float4* __restrict__ ew4,
                                                    int* __restrict__ cursor,
                                                    int* __restrict__ eid,
                                                    float* __restrict__ ews) {
  int q = blockIdx.x * 256 + threadIdx.x;
  if (q < NE / 4) {
    int4 t = tgt4[q];
    float4 w = ew4[q];
    int e = q * 4;
    int p;
    p = atomicAdd(&cursor[t.x], 1); eid[p] = e;     ews[p] = w.x;
    p = atomicAdd(&cursor[t.y], 1); eid[p] = e + 1; ews[p] = w.y;
    p = atomicAdd(&cursor[t.z], 1); eid[p] = e + 2; ews[p] = w.z;
    p = atomicAdd(&cursor[t.w], 1); eid[p] = e + 3; ews[p] = w.w;
  }
}

// ---- 4. gather-aggregate: one wave per node; 16 edges in flight ----
__global__ __launch_bounds__(256) void agg_kernel(
    const int* __restrict__ offs, const int* __restrict__ eid,
    const float* __restrict__ ews, const float* __restrict__ ea,
    const float* __restrict__ nwt, ushort* __restrict__ mean_bf) {
  int lane = threadIdx.x & 63;
  int n = blockIdx.x * 4 + (threadIdx.x >> 6);
  if (n >= NN) return;
  int jbeg = offs[n], jend = offs[n + 1];
  int deg = jend - jbeg;
  int eg = lane >> 4;   // edge slot 0..3
  int fq = lane & 15;   // feature quad -> floats 4*fq..4*fq+3

  f32x4 acc = (f32x4)(0.0f);
  for (int j = jbeg; j < jend; j += 16) {
#pragma unroll
    for (int u = 0; u < 4; ++u) {
      int i = j + u * 4 + eg;
      int c = min(i, jend - 1);
      float w = (i < jend) ? ews[c] : 0.0f;
      int e = eid[c];
      f32x4 v = *(const f32x4*)(ea + (size_t)e * EF + fq * 4);
      acc += v * w;
    }
  }

  // reduce across the 4 edge slots (lane bits 4,5)
#pragma unroll
  for (int m = 16; m <= 32; m <<= 1) {
    f32x4 o;
#pragma unroll
    for (int i = 0; i < 4; ++i) o[i] = __shfl_xor(acc[i], m, 64);
    acc += o;
  }

  if (lane < 16) {
    float scale = nwt[n] / (float)max(deg, 1);
    ushort4 o;
    o.x = f2bf(acc[0] * scale);
    o.y = f2bf(acc[1] * scale);
    o.z = f2bf(acc[2] * scale);
    o.w = f2bf(acc[3] * scale);
    *(ushort4*)(mean_bf + (size_t)n * EF + fq * 4) = o;
  }
}

// ---- fused concat + GEMM + bias + relu ----
__global__ __launch_bounds__(256) void gemm_kernel(
    const float* __restrict__ na, const ushort* __restrict__ mean_bf,
    const ushort* __restrict__ wfrag, const float* __restrict__ bias,
    float* __restrict__ out) {
  int tid = threadIdx.x;
  int lane = tid & 63;
  int wv = tid >> 6;
  int row_base = blockIdx.x * 64 + wv * 16;
  int r = row_base + (lane & 15);
  int rc = min(r, NN - 1);          // clamp tail; stores are guarded
  int kofs = (lane >> 4) * 8;       // element offset within a K=32 step
  int colb = lane & 15;

  const float* narow = na + (size_t)rc * IC;
  const ushort* mrow = mean_bf + (size_t)rc * EF;

  bf16x8 afrag[6];
#pragma unroll
  for (int s = 0; s < 4; ++s) {
    f32x4 lo = *(const f32x4*)(narow + s * 32 + kofs);
    f32x4 hi = *(const f32x4*)(narow + s * 32 + kofs + 4);
#pragma unroll
    for (int i = 0; i < 4; ++i) {
      afrag[s][i] = (short)f2bf(lo[i]);
      afrag[s][4 + i] = (short)f2bf(hi[i]);
    }
  }
#pragma unroll
  for (int s = 0; s < 2; ++s)
    afrag[4 + s] = *(const bf16x8*)(mrow + s * 32 + kofs);

  f32x4 acc[16];
#pragma unroll
  for (int ct = 0; ct < 16; ++ct) acc[ct] = (f32x4)(0.0f);

#pragma unroll
  for (int s = 0; s < 6; ++s) {
#pragma unroll
    for (int ct = 0; ct < 16; ++ct) {
      bf16x8 bfrag =
          *(const bf16x8*)(wfrag + ((size_t)((s * 16 + ct) * 64 + lane) * 8));
      acc[ct] =
          __builtin_amdgcn_mfma_f32_16x16x32_bf16(afrag[s], bfrag, acc[ct], 0, 0, 0);
    }
  }

  // C/D layout (m89-verified): col = lane&15, row = (lane>>4)*4 + reg
#pragma unroll
  for (int ct = 0; ct < 16; ++ct) {
    int col = ct * 16 + colb;
    float bv = bias[col];
#pragma unroll
    for (int i = 0; i < 4; ++i) {
      int rr = row_base + (lane >> 4) * 4 + i;
      if (rr < NN) {
        float v = fmaxf(acc[ct][i] + bv, 0.0f);
        __builtin_nontemporal_store(v, out + (size_t)rr * OC + col);
      }
    }
  }
}

extern "C" void kernel_launch(void* const* d_in, const int* in_sizes, int n_in,
                              void* d_out, int out_size, void* d_ws, size_t ws_size,
                              hipStream_t stream) {
  const int* edge_index = (const int*)d_in[0];    // [2][NE], row 0 = targets
  const float* edge_attr = (const float*)d_in[1]; // [NE][EF]
  const float* node_attr = (const float*)d_in[2]; // [NN][IC]
  const float* edge_weight = (const float*)d_in[3];
  const float* node_weight = (const float*)d_in[4];
  const float* W = (const float*)d_in[5];         // [192][256]
  const float* bias = (const float*)d_in[6];
  float* out = (float*)d_out;

  char* p = (char*)d_ws;
  ushort* mean_bf = (ushort*)p;                    // 12,800,000 B
  int* eid       = (int*)(p + 12800000);           // 4,000,000 B
  float* ews     = (float*)(p + 16800000);         // 4,000,000 B
  int* cnt       = (int*)(p + 20800000);           // 400,000 B
  int* offs      = (int*)(p + 21200000);           // 400,016 B
  int* cursor    = (int*)(p + 21600016);           // 400,000 B
  int* bsum      = (int*)(p + 22000016);           // 1,568 B
  ushort* wfrag  = (ushort*)(p + 22001600);        // 98,304 B (16B-aligned)

  wprep_kernel<<<192, 256, 0, stream>>>(W, wfrag, cnt);
  hist_kernel<<<(NE / 4 + 255) / 256, 256, 0, stream>>>((const int4*)edge_index,
                                                        cnt);
  scan1_kernel<<<NB1, 256, 0, stream>>>(cnt, bsum);
  scan23_kernel<<<NB1, 256, 0, stream>>>(cnt, bsum, offs, cursor);
  place_kernel<<<(NE / 4 + 255) / 256, 256, 0, stream>>>(
      (const int4*)edge_index, (const float4*)edge_weight, cursor, eid, ews);
  agg_kernel<<<(NN + 3) / 4, 256, 0, stream>>>(offs, eid, ews, edge_attr,
                                               node_weight, mean_bf);
  gemm_kernel<<<(NN + 63) / 64, 256, 0, stream>>>(node_attr, mean_bf, wfrag,
                                                  bias, out);
}